// Round 10
// baseline (535.809 us; speedup 1.0000x reference)
//
#include <hip/hip_runtime.h>
#include <math.h>

// BlockwiseEarlyExitMamba: B=128, L=64, EXIT_POS=32 -> only t<32 matter.
// 11 kernels: prep + tok + [inproj GEMM + fused-rest]x4 + cls.
// All tensors packed: one uint32 = (bf16_hi << 16) | bf16_lo  (split-bf16).
#define BATCH 128
#define TOKENS 4096

using bf16x8 = __attribute__((ext_vector_type(8))) short;
using f32x4  = __attribute__((ext_vector_type(4))) float;
typedef unsigned short ushort_t;
typedef unsigned int   uint_t;

#define NIP (4*1024*256)
#define NOP (4*256*512)
#define NXP (4*64*512)     // xproj padded 48->64 rows
#define NFW (256*160)      // fusion_w padded 136->160 cols
#define NPREP (NIP+NOP+NXP+NFW)

// ---------------- helpers ----------------
__device__ __forceinline__ float silu_f(float x) { return x / (1.f + __expf(-x)); }
__device__ __forceinline__ ushort_t bf16_rne(float f) {
  unsigned int u = __float_as_uint(f);
  u += 0x7FFFu + ((u >> 16) & 1u);
  return (ushort_t)(u >> 16);
}
__device__ __forceinline__ float bf16_to_f(ushort_t h) {
  return __uint_as_float(((unsigned int)h) << 16);
}
__device__ __forceinline__ uint_t packf(float f) {
  ushort_t h = bf16_rne(f);
  ushort_t l = bf16_rne(f - bf16_to_f(h));
  return ((uint_t)h << 16) | (uint_t)l;
}
__device__ __forceinline__ float unpackf(uint_t u) {
  return bf16_to_f((ushort_t)(u >> 16)) + bf16_to_f((ushort_t)(u & 0xffff));
}
// 8 packed uints (8 k-elements) -> hi bf16x8 + lo bf16x8 via v_perm_b32
union U4V { uint4 q; bf16x8 v; };
__device__ __forceinline__ void unpack_frag8(const uint_t* p, bf16x8& fh, bf16x8& fl) {
  uint4 a = *(const uint4*)p;
  uint4 b = *(const uint4*)(p + 4);
  U4V H, L;
  H.q.x = __builtin_amdgcn_perm(a.y, a.x, 0x07060302u);
  L.q.x = __builtin_amdgcn_perm(a.y, a.x, 0x05040100u);
  H.q.y = __builtin_amdgcn_perm(a.w, a.z, 0x07060302u);
  L.q.y = __builtin_amdgcn_perm(a.w, a.z, 0x05040100u);
  H.q.z = __builtin_amdgcn_perm(b.y, b.x, 0x07060302u);
  L.q.z = __builtin_amdgcn_perm(b.y, b.x, 0x05040100u);
  H.q.w = __builtin_amdgcn_perm(b.w, b.z, 0x07060302u);
  L.q.w = __builtin_amdgcn_perm(b.w, b.z, 0x05040100u);
  fh = H.v; fl = L.v;
}
#define MFMA3(acc, fah, fal, fbh, fbl)                                        \
  acc = __builtin_amdgcn_mfma_f32_16x16x32_bf16(fah, fbh, acc, 0, 0, 0);      \
  acc = __builtin_amdgcn_mfma_f32_16x16x32_bf16(fah, fbl, acc, 0, 0, 0);      \
  acc = __builtin_amdgcn_mfma_f32_16x16x32_bf16(fal, fbh, acc, 0, 0, 0);

// ---------------- prep: fp32 weights -> packed split-bf16 ----------------
__global__ __launch_bounds__(256) void prep_w(
    const float* __restrict__ ipw, const float* __restrict__ opw,
    const float* __restrict__ xpw, const float* __restrict__ fw,
    uint_t* __restrict__ ipw_p, uint_t* __restrict__ opw_p,
    uint_t* __restrict__ xpw_p, uint_t* __restrict__ fw_p) {
  for (int i = blockIdx.x*256 + threadIdx.x; i < NPREP; i += 512*256) {
    if (i < NIP) {
      ipw_p[i] = packf(ipw[i]);
    } else if (i < NIP+NOP) {
      int j = i - NIP;
      opw_p[j] = packf(opw[j]);
    } else if (i < NIP+NOP+NXP) {
      int j = i - (NIP+NOP);
      int lay = j >> 15; int r = (j >> 9) & 63, c = j & 511;
      float v = (r < 48) ? xpw[(size_t)lay*48*512 + r*512 + c] : 0.f;
      xpw_p[j] = packf(v);
    } else {
      int j = i - (NIP+NOP+NXP);
      int r = j / 160, c = j - r*160;
      float v = (c < 136) ? fw[r*136 + c] : 0.f;
      fw_p[j] = packf(v);
    }
  }
}

// ---------------- tokenizer: cat -> GEMM(K=160) -> LN -> feat_p --------------
#define CAT_STR 164
__global__ __launch_bounds__(256) void tok_kernel(
    const float* __restrict__ x,  const float* __restrict__ ep,
    const float* __restrict__ ef, const float* __restrict__ ed,
    const float* __restrict__ plw, const float* __restrict__ plb,
    const float* __restrict__ piw, const float* __restrict__ pib,
    const uint_t* __restrict__ fw_p, const float* __restrict__ g,
    const float* __restrict__ bb, uint_t* __restrict__ feat_p) {
  __shared__ __align__(16) uint_t sC[32*CAT_STR];
  __shared__ float sRed[512];
  const int tid = threadIdx.x, b = blockIdx.x;
  const int wave = tid >> 6, lane = tid & 63, lm = lane & 15, lq = lane >> 4;
  for (int idx = tid; idx < 32*160; idx += 256) {
    int t = idx / 160, c = idx - t*160;
    const float* xr = x + ((size_t)b*64 + t)*5;   // original L=64 stride
    float x0=xr[0], x1=xr[1], x2=xr[2], x3=xr[3], x4=xr[4];
    float v;
    if (c < 32)       { int pr = min(max((int)x0,0),255); v = ep[pr*32+c]; }
    else if (c < 64)    v = x1*plw[c-32] + plb[c-32];
    else if (c < 96)  { int fl = min(max((int)x2,0),63); v = ef[fl*32+(c-64)]; }
    else if (c < 128)   v = x3*piw[c-96] + pib[c-96];
    else if (c < 136) { int dr = min(max((int)x4,0),1); v = ed[dr*8+(c-128)]; }
    else                v = 0.f;
    sC[t*CAT_STR + c] = packf(v);
  }
  __syncthreads();
  f32x4 acc[2][4];
  #pragma unroll
  for (int i=0;i<2;++i)
    #pragma unroll
    for (int j=0;j<4;++j) acc[i][j] = (f32x4){0.f,0.f,0.f,0.f};
  for (int k0 = 0; k0 < 160; k0 += 32) {
    bf16x8 ah[2], al[2];
    #pragma unroll
    for (int mi=0; mi<2; ++mi)
      unpack_frag8(sC + (mi*16+lm)*CAT_STR + k0 + lq*8, ah[mi], al[mi]);
    #pragma unroll
    for (int nt=0; nt<4; ++nt) {
      int n = wave*64 + nt*16 + lm;
      bf16x8 wh, wl;
      unpack_frag8(fw_p + (size_t)n*160 + k0 + lq*8, wh, wl);
      #pragma unroll
      for (int mi=0; mi<2; ++mi) { MFMA3(acc[mi][nt], ah[mi], al[mi], wh, wl); }
    }
  }
  float s[2][4], q[2][4];
  #pragma unroll
  for (int mi=0; mi<2; ++mi)
    #pragma unroll
    for (int r=0; r<4; ++r) {
      s[mi][r] = acc[mi][0][r]+acc[mi][1][r]+acc[mi][2][r]+acc[mi][3][r];
      q[mi][r] = acc[mi][0][r]*acc[mi][0][r]+acc[mi][1][r]*acc[mi][1][r]
               + acc[mi][2][r]*acc[mi][2][r]+acc[mi][3][r]*acc[mi][3][r];
    }
  #pragma unroll
  for (int off=1; off<16; off<<=1)
    #pragma unroll
    for (int mi=0; mi<2; ++mi)
      #pragma unroll
      for (int r=0; r<4; ++r) {
        s[mi][r] += __shfl_xor(s[mi][r], off);
        q[mi][r] += __shfl_xor(q[mi][r], off);
      }
  if (lm == 0)
    #pragma unroll
    for (int mi=0; mi<2; ++mi)
      #pragma unroll
      for (int r=0; r<4; ++r) {
        int row = mi*16 + lq*4 + r;
        sRed[row*8 + wave*2]   = s[mi][r];
        sRed[row*8 + wave*2+1] = q[mi][r];
      }
  __syncthreads();
  #pragma unroll
  for (int mi=0; mi<2; ++mi)
    #pragma unroll
    for (int r=0; r<4; ++r) {
      int row = mi*16 + lq*4 + r;
      float S=0.f, Q=0.f;
      #pragma unroll
      for (int w4=0; w4<4; ++w4) { S += sRed[row*8+w4*2]; Q += sRed[row*8+w4*2+1]; }
      float mu = S*(1.f/256.f);
      float rs = rsqrtf(Q*(1.f/256.f) - mu*mu + 1e-5f);
      #pragma unroll
      for (int nt=0; nt<4; ++nt) {
        int n = wave*64 + nt*16 + lm;
        float o = (acc[mi][nt][r]-mu)*rs*g[n] + bb[n];
        feat_p[((size_t)(b*32+row))*256 + n] = packf(o);
      }
    }
}

// ---------------- A: in_proj GEMM, double-buffered staging -------------------
// grid (8, 32) = (bn, bm), 512 threads = 8 waves (2 M x 4 N), tile 128x128.
#define GA_STR 36
__global__ __launch_bounds__(512) void inproj_kernel(
    const uint_t* __restrict__ feat_p, const uint_t* __restrict__ ipw_p,
    uint_t* __restrict__ xz_p) {
  __shared__ __align__(16) uint_t sA[2*128*GA_STR];
  __shared__ __align__(16) uint_t sW[2*128*GA_STR];
  const int tid = threadIdx.x;
  const int wave = tid >> 6, lane = tid & 63, lm = lane & 15, lq = lane >> 4;
  const int wm = (wave & 1)*64, wn = (wave >> 1)*32;
  const int m0 = blockIdx.y*128, n0 = blockIdx.x*128;
  const int srow = tid >> 3, sc4 = (tid & 7)*4;   // staging: 2 rows per thread
  f32x4 acc[4][2];
  #pragma unroll
  for (int i=0;i<4;++i)
    #pragma unroll
    for (int j=0;j<2;++j) acc[i][j] = (f32x4){0.f,0.f,0.f,0.f};
  uint4 va[2], vw[2];
  #pragma unroll
  for (int i=0;i<2;++i) {
    int row = srow + i*64;
    va[i] = *(const uint4*)(feat_p + ((size_t)(m0+row))*256 + sc4);
    vw[i] = *(const uint4*)(ipw_p  + ((size_t)(n0+row))*256 + sc4);
  }
  #pragma unroll
  for (int i=0;i<2;++i) {
    int row = srow + i*64;
    *(uint4*)(sA + row*GA_STR + sc4) = va[i];
    *(uint4*)(sW + row*GA_STR + sc4) = vw[i];
  }
  __syncthreads();
  for (int ks = 0; ks < 8; ++ks) {
    uint_t* bufA = sA + (ks & 1)*128*GA_STR;
    uint_t* bufW = sW + (ks & 1)*128*GA_STR;
    if (ks < 7) {
      int k0 = (ks+1)*32;
      #pragma unroll
      for (int i=0;i<2;++i) {
        int row = srow + i*64;
        va[i] = *(const uint4*)(feat_p + ((size_t)(m0+row))*256 + k0 + sc4);
        vw[i] = *(const uint4*)(ipw_p  + ((size_t)(n0+row))*256 + k0 + sc4);
      }
    }
    bf16x8 ah[4], al[4], wh[2], wl[2];
    #pragma unroll
    for (int mi=0; mi<4; ++mi)
      unpack_frag8(bufA + (wm+mi*16+lm)*GA_STR + lq*8, ah[mi], al[mi]);
    #pragma unroll
    for (int nt=0; nt<2; ++nt)
      unpack_frag8(bufW + (wn+nt*16+lm)*GA_STR + lq*8, wh[nt], wl[nt]);
    #pragma unroll
    for (int mi=0; mi<4; ++mi)
      #pragma unroll
      for (int nt=0; nt<2; ++nt) { MFMA3(acc[mi][nt], ah[mi], al[mi], wh[nt], wl[nt]); }
    if (ks < 7) {
      uint_t* nA = sA + ((ks+1) & 1)*128*GA_STR;
      uint_t* nW = sW + ((ks+1) & 1)*128*GA_STR;
      #pragma unroll
      for (int i=0;i<2;++i) {
        int row = srow + i*64;
        *(uint4*)(nA + row*GA_STR + sc4) = va[i];
        *(uint4*)(nW + row*GA_STR + sc4) = vw[i];
      }
      __syncthreads();
    }
  }
  #pragma unroll
  for (int mi=0; mi<4; ++mi)
    #pragma unroll
    for (int nt=0; nt<2; ++nt) {
      int n = n0 + wn + nt*16 + lm;
      #pragma unroll
      for (int r=0; r<4; ++r) {
        int tok = m0 + wm + mi*16 + lq*4 + r;
        xz_p[(size_t)tok*1024 + n] = packf(acc[mi][nt][r]);
      }
    }
}

// ---------------- B: conv+silu + xproj + scan + gate + outproj + LN ----------
// 128 blocks (one per batch) x 512 threads (8 waves).
// z preloaded to regs; outproj W staged through double-buffered LDS.
#define SU_STR 520
#define WCH (256*36)     // one W chunk buffer (uints)
__global__ __launch_bounds__(512) void layer_kernel(
    const uint_t* __restrict__ xz_p,
    const float* __restrict__ cw, const float* __restrict__ cb,
    const uint_t* __restrict__ xpw_p,
    const float* __restrict__ dpw, const float* __restrict__ dpb,
    const float* __restrict__ alog, const float* __restrict__ dsk,
    const uint_t* __restrict__ opw_p,
    const float* __restrict__ lng, const float* __restrict__ lnb,
    uint_t* __restrict__ feat_p) {
  __shared__ __align__(16) uint_t sU[32*SU_STR];   // 66.5 KB: u, then y
  __shared__ __align__(16) uint_t sW[2*WCH];       // 72 KB: opw chunks
  __shared__ float sD[2*2048];                     // 16 KB: xproj partials
  __shared__ float sRed[512];
  const int tid = threadIdx.x, b = blockIdx.x;
  const int wave = tid >> 6, lane = tid & 63, lm = lane & 15, lq = lane >> 4;
  // preload z column (own channel) into regs -- coalesced, pipelined
  uint_t zreg[32];
  #pragma unroll
  for (int t=0; t<32; ++t)
    zreg[t] = xz_p[((size_t)(b*32+t))*1024 + 512 + tid];
  // stage u-half of xz (32 x 512 packed)
  for (int idx = tid; idx < 4096; idx += 512) {
    int t = idx >> 7, c4 = (idx & 127)*4;
    *(uint4*)(sU + t*SU_STR + c4) =
        *(const uint4*)(xz_p + ((size_t)(b*32+t))*1024 + c4);
  }
  __syncthreads();
  // conv + silu in place (thread owns channel d = tid)
  {
    int d = tid;
    const float* cwl = cw + d*4;
    float c0=cwl[0], c1=cwl[1], c2=cwl[2], c3=cwl[3];
    float bias = cb[d];
    float p3=0.f, p2=0.f, p1=0.f;
    #pragma unroll
    for (int t=0; t<32; ++t) {
      float xv = unpackf(sU[t*SU_STR + d]);
      float a = bias + c0*p3 + c1*p2 + c2*p1 + c3*xv;
      float u = silu_f(a);
      p3=p2; p2=p1; p1=xv;
      sU[t*SU_STR + d] = packf(u);
    }
  }
  __syncthreads();
  // xproj: 8 waves = 2 K-halves x 4 row-groups(16)
  {
    const int kh = wave >> 2, nr = wave & 3;
    f32x4 ax[2] = {(f32x4){0.f,0.f,0.f,0.f}, (f32x4){0.f,0.f,0.f,0.f}};
    for (int k0 = 0; k0 < 256; k0 += 32) {
      bf16x8 ah[2], al[2];
      #pragma unroll
      for (int mi=0; mi<2; ++mi)
        unpack_frag8(sU + (mi*16+lm)*SU_STR + kh*256 + k0 + lq*8, ah[mi], al[mi]);
      bf16x8 wh, wl;
      unpack_frag8(xpw_p + (size_t)(nr*16+lm)*512 + kh*256 + k0 + lq*8, wh, wl);
      #pragma unroll
      for (int mi=0; mi<2; ++mi) { MFMA3(ax[mi], ah[mi], al[mi], wh, wl); }
    }
    float* dst = sD + kh*2048;
    #pragma unroll
    for (int mi=0; mi<2; ++mi)
      #pragma unroll
      for (int r=0; r<4; ++r) {
        int row = mi*16 + lq*4 + r;
        dst[row*64 + nr*16 + lm] = ax[mi][r];
      }
  }
  __syncthreads();
  for (int i = tid; i < 2048; i += 512) sD[i] += sD[i + 2048];
  __syncthreads();
  // dtproj + scan + gate; thread owns channel d = tid; y -> sU (packed)
  {
    int d = tid;
    float w[16], cc[16], hh[16];
    #pragma unroll
    for (int r=0; r<16; ++r) w[r] = dpw[d*16 + r];
    #pragma unroll
    for (int n=0; n<16; ++n) {
      cc[n] = -__expf(alog[d*16+n]) * 1.4426950408889634f;
      hh[n] = 0.f;
    }
    float bias = dpb[d], dskv = dsk[d];
    #pragma unroll
    for (int t=0; t<32; ++t) {
      const float* row = sD + t*64;
      float raw = bias;
      #pragma unroll
      for (int r=0; r<16; ++r) raw += w[r]*row[r];
      float dtv = (raw > 20.f) ? raw : __logf(1.f + __expf(raw));
      float uv = unpackf(sU[t*SU_STR + d]);
      float du = dtv*uv, yv = 0.f;
      #pragma unroll
      for (int n=0; n<16; ++n) {
        float e = exp2f(dtv*cc[n]);
        hh[n] = e*hh[n] + du*row[16+n];
        yv += hh[n]*row[32+n];
      }
      float zv = unpackf(zreg[t]);
      float y = (yv + uv*dskv) * silu_f(zv);
      sU[t*SU_STR + d] = packf(y);   // own column; read-before-write per t
    }
  }
  __syncthreads();
  // outproj: wave owns 32 cols; K=512 in 16 chunks, W double-buffered in LDS
  f32x4 ao[2][2];
  #pragma unroll
  for (int i=0;i<2;++i)
    #pragma unroll
    for (int j=0;j<2;++j) ao[i][j] = (f32x4){0.f,0.f,0.f,0.f};
  const int srow = tid >> 1, sc4 = (tid & 1)*4;   // W staging: 256r x 8 uint4
  uint4 wv[4];
  #pragma unroll
  for (int i=0;i<4;++i) {
    int row = (srow + i*256) & 255, c4 = sc4 + ((srow + i*256) >> 8)*8;
    (void)row;
  }
  // simpler staging map: idx = tid + i*512 -> row = idx>>3 (0..255), c4=(idx&7)*4
  #pragma unroll
  for (int i=0;i<4;++i) {
    int idx = tid + i*512;
    int row = idx >> 3, c4 = (idx & 7)*4;
    wv[i] = *(const uint4*)(opw_p + (size_t)row*512 + c4);
  }
  #pragma unroll
  for (int i=0;i<4;++i) {
    int idx = tid + i*512;
    int row = idx >> 3, c4 = (idx & 7)*4;
    *(uint4*)(sW + row*GA_STR + c4) = wv[i];
  }
  __syncthreads();
  for (int kc = 0; kc < 16; ++kc) {
    uint_t* buf = sW + (kc & 1)*WCH;
    if (kc < 15) {
      int k0 = (kc+1)*32;
      #pragma unroll
      for (int i=0;i<4;++i) {
        int idx = tid + i*512;
        int row = idx >> 3, c4 = (idx & 7)*4;
        wv[i] = *(const uint4*)(opw_p + (size_t)row*512 + k0 + c4);
      }
    }
    bf16x8 ah[2], al[2];
    #pragma unroll
    for (int mi=0; mi<2; ++mi)
      unpack_frag8(sU + (mi*16+lm)*SU_STR + kc*32 + lq*8, ah[mi], al[mi]);
    #pragma unroll
    for (int nt=0; nt<2; ++nt) {
      int n = wave*32 + nt*16 + lm;
      bf16x8 wh, wl;
      unpack_frag8(buf + n*GA_STR + lq*8, wh, wl);
      #pragma unroll
      for (int mi=0; mi<2; ++mi) { MFMA3(ao[mi][nt], ah[mi], al[mi], wh, wl); }
    }
    if (kc < 15) {
      uint_t* nbuf = sW + ((kc+1) & 1)*WCH;
      #pragma unroll
      for (int i=0;i<4;++i) {
        int idx = tid + i*512;
        int row = idx >> 3, c4 = (idx & 7)*4;
        *(uint4*)(nbuf + row*GA_STR + c4) = wv[i];
      }
      __syncthreads();
    }
  }
  // residual + LN -> feat_p
  float v[2][2][4];
  #pragma unroll
  for (int mi=0; mi<2; ++mi)
    #pragma unroll
    for (int nt=0; nt<2; ++nt)
      #pragma unroll
      for (int r=0; r<4; ++r) {
        int row = mi*16 + lq*4 + r, n = wave*32 + nt*16 + lm;
        v[mi][nt][r] = ao[mi][nt][r]
                     + unpackf(feat_p[((size_t)(b*32+row))*256 + n]);
      }
  float s[2][4], q[2][4];
  #pragma unroll
  for (int mi=0; mi<2; ++mi)
    #pragma unroll
    for (int r=0; r<4; ++r) {
      float a = v[mi][0][r], c = v[mi][1][r];
      s[mi][r] = a + c; q[mi][r] = a*a + c*c;
    }
  #pragma unroll
  for (int off=1; off<16; off<<=1)
    #pragma unroll
    for (int mi=0; mi<2; ++mi)
      #pragma unroll
      for (int r=0; r<4; ++r) {
        s[mi][r] += __shfl_xor(s[mi][r], off);
        q[mi][r] += __shfl_xor(q[mi][r], off);
      }
  if (lm == 0)
    #pragma unroll
    for (int mi=0; mi<2; ++mi)
      #pragma unroll
      for (int r=0; r<4; ++r) {
        int row = mi*16 + lq*4 + r;
        sRed[(row*8 + wave)*2]   = s[mi][r];
        sRed[(row*8 + wave)*2+1] = q[mi][r];
      }
  __syncthreads();
  #pragma unroll
  for (int mi=0; mi<2; ++mi)
    #pragma unroll
    for (int r=0; r<4; ++r) {
      int row = mi*16 + lq*4 + r;
      float S=0.f, Q=0.f;
      #pragma unroll
      for (int w8=0; w8<8; ++w8) { S += sRed[(row*8+w8)*2]; Q += sRed[(row*8+w8)*2+1]; }
      float mu = S*(1.f/256.f);
      float rs = rsqrtf(Q*(1.f/256.f) - mu*mu + 1e-5f);
      #pragma unroll
      for (int nt=0; nt<2; ++nt) {
        int n = wave*32 + nt*16 + lm;
        float o = (v[mi][nt][r]-mu)*rs*lng[n] + lnb[n];
        feat_p[((size_t)(b*32+row))*256 + n] = packf(o);
      }
    }
}

// ---------------- classifier ----------------
__global__ __launch_bounds__(128) void cls_kernel(
    const uint_t* __restrict__ feat_p, const float* __restrict__ w1,
    const float* __restrict__ b1,  const float* __restrict__ w2,
    const float* __restrict__ b2,  float* __restrict__ out) {
  __shared__ float hrow[256];
  __shared__ float hid[128];
  int tid = threadIdx.x, b = blockIdx.x;
  const uint_t* fr = feat_p + ((size_t)(b*32+31))*256;   // EXIT_POS-1 = 31
  hrow[tid]     = unpackf(fr[tid]);
  hrow[tid+128] = unpackf(fr[tid+128]);
  __syncthreads();
  float acc = b1[tid];
  const float* wr = w1 + (size_t)tid*256;
  #pragma unroll 8
  for (int k = 0; k < 256; ++k) acc += wr[k]*hrow[k];
  hid[tid] = fmaxf(acc, 0.f);
  __syncthreads();
  if (tid < 2) {
    float o = b2[tid];
    const float* w2r = w2 + (size_t)tid*128;
    for (int k = 0; k < 128; ++k) o += w2r[k]*hid[k];
    out[b*2 + tid] = o;
  }
}

// ---------------- launch ----------------
extern "C" void kernel_launch(void* const* d_in, const int* in_sizes, int n_in,
                              void* d_out, int out_size, void* d_ws, size_t ws_size,
                              hipStream_t stream) {
  const float* x    = (const float*)d_in[0];
  const float* ep   = (const float*)d_in[1];
  const float* ef   = (const float*)d_in[2];
  const float* ed   = (const float*)d_in[3];
  const float* plw  = (const float*)d_in[4];
  const float* plb  = (const float*)d_in[5];
  const float* piw  = (const float*)d_in[6];
  const float* pib  = (const float*)d_in[7];
  const float* fw   = (const float*)d_in[8];
  const float* tng  = (const float*)d_in[10];
  const float* tnb  = (const float*)d_in[11];
  const float* ipw  = (const float*)d_in[12];
  const float* cw   = (const float*)d_in[13];
  const float* cb   = (const float*)d_in[14];
  const float* xpw  = (const float*)d_in[15];
  const float* dpw  = (const float*)d_in[16];
  const float* dpb  = (const float*)d_in[17];
  const float* alog = (const float*)d_in[18];
  const float* dsk  = (const float*)d_in[19];
  const float* opw  = (const float*)d_in[20];
  const float* lng  = (const float*)d_in[21];
  const float* lnb  = (const float*)d_in[22];
  const float* w1   = (const float*)d_in[23];
  const float* b1   = (const float*)d_in[24];
  const float* w2   = (const float*)d_in[25];
  const float* b2   = (const float*)d_in[26];

  uint_t* up = (uint_t*)d_ws;
  uint_t* ipw_p = up;                 up += (size_t)NIP;
  uint_t* opw_p = up;                 up += (size_t)NOP;
  uint_t* xpw_p = up;                 up += (size_t)NXP;
  uint_t* fw_p  = up;                 up += (size_t)NFW;
  uint_t* feat_p = up;                up += (size_t)TOKENS*256;
  uint_t* xz_p   = up;                up += (size_t)TOKENS*1024;

  prep_w<<<512, 256, 0, stream>>>(ipw, opw, xpw, fw, ipw_p, opw_p, xpw_p, fw_p);
  tok_kernel<<<BATCH, 256, 0, stream>>>(x, ep, ef, ed, plw, plb, piw, pib,
                                        fw_p, tng, tnb, feat_p);
  for (int l = 0; l < 4; ++l) {
    inproj_kernel<<<dim3(8, 32), 512, 0, stream>>>(
        feat_p, ipw_p + (size_t)l*262144, xz_p);
    layer_kernel<<<BATCH, 512, 0, stream>>>(
        xz_p, cw + (size_t)l*2048, cb + (size_t)l*512,
        xpw_p + (size_t)l*32768,
        dpw + (size_t)l*8192, dpb + (size_t)l*512,
        alog + (size_t)l*8192, dsk + (size_t)l*512,
        opw_p + (size_t)l*131072, lng, lnb, feat_p);
  }
  cls_kernel<<<BATCH, 128, 0, stream>>>(feat_p, w1, b1, w2, b2, (float*)d_out);
}